// Round 1
// baseline (1316.823 us; speedup 1.0000x reference)
//
#include <hip/hip_runtime.h>
#include <math.h>

#define BSZ 4
#define DM 256
#define HH 256
#define WW 256
#define LL 256
#define DI 512
#define NBL (BSZ * LL)  // 1024

// ---------------- phase A: x_h = mean over W ----------------
// one 64-lane wave per (b,d,h) row; output written as sequence layout (b, l=h, dm)
__global__ __launch_bounds__(256) void k_mean_w(const float* __restrict__ x0,
                                                float* __restrict__ xseq) {
    int wave = (blockIdx.x * blockDim.x + threadIdx.x) >> 6;
    int lane = threadIdx.x & 63;
    int b = wave >> 16;
    int d = (wave >> 8) & 255;
    int h = wave & 255;
    const float4* row = (const float4*)(x0 + (size_t)wave * WW);
    float4 v = row[lane];
    float s = v.x + v.y + v.z + v.w;
#pragma unroll
    for (int m = 32; m >= 1; m >>= 1) s += __shfl_xor(s, m);
    if (lane == 0) xseq[((size_t)(b * LL) + h) * DM + d] = s * (1.0f / WW);
}

// ---------------- generic fp32 GEMM: C[M,N] = A[M,K] * B[N,K]^T ----------------
// M,N multiples of 64; K multiple of 16. 256 threads, 64x64 tile, 4x4 micro.
__global__ __launch_bounds__(256) void k_gemm_nt(const float* __restrict__ A,
                                                 const float* __restrict__ Bw,
                                                 float* __restrict__ C,
                                                 int M, int N, int K) {
    __shared__ float As[16][64];
    __shared__ float Bs[16][64];
    int tid = threadIdx.x;
    int tx = tid & 15, ty = tid >> 4;
    int n0 = blockIdx.x * 64;
    int m0 = blockIdx.y * 64;
    int lr = tid >> 2;        // 0..63 row within tile
    int lk = (tid & 3) * 4;   // 0,4,8,12 k-offset

    float acc[4][4];
#pragma unroll
    for (int i = 0; i < 4; ++i)
#pragma unroll
        for (int j = 0; j < 4; ++j) acc[i][j] = 0.0f;

    for (int k0 = 0; k0 < K; k0 += 16) {
        float4 a = *(const float4*)(A + (size_t)(m0 + lr) * K + k0 + lk);
        float4 b = *(const float4*)(Bw + (size_t)(n0 + lr) * K + k0 + lk);
        __syncthreads();
        As[lk + 0][lr] = a.x; As[lk + 1][lr] = a.y; As[lk + 2][lr] = a.z; As[lk + 3][lr] = a.w;
        Bs[lk + 0][lr] = b.x; Bs[lk + 1][lr] = b.y; Bs[lk + 2][lr] = b.z; Bs[lk + 3][lr] = b.w;
        __syncthreads();
#pragma unroll
        for (int kk = 0; kk < 16; ++kk) {
            float4 af = *(const float4*)(&As[kk][ty << 2]);
            float4 bf = *(const float4*)(&Bs[kk][tx << 2]);
            float aa[4] = {af.x, af.y, af.z, af.w};
            float bb[4] = {bf.x, bf.y, bf.z, bf.w};
#pragma unroll
            for (int i = 0; i < 4; ++i)
#pragma unroll
                for (int j = 0; j < 4; ++j) acc[i][j] = fmaf(aa[i], bb[j], acc[i][j]);
        }
    }
#pragma unroll
    for (int i = 0; i < 4; ++i)
#pragma unroll
        for (int j = 0; j < 4; ++j)
            C[(size_t)(m0 + (ty << 2) + i) * N + n0 + (tx << 2) + j] = acc[i][j];
}

// ---------------- causal depthwise conv (D_CONV=4) + silu ----------------
__global__ __launch_bounds__(256) void k_conv_silu(const float* __restrict__ xz,
                                                   const float* __restrict__ cw,
                                                   const float* __restrict__ cb,
                                                   float* __restrict__ xx) {
    int t = blockIdx.x * 256 + threadIdx.x;  // (b,l,d), d fastest
    int d = t & (DI - 1);
    int bl = t >> 9;
    int l = bl & (LL - 1);
    int b = bl >> 8;
    float acc = cb[d];
#pragma unroll
    for (int k = 0; k < 4; ++k) {
        int ls = l + k - 3;
        float v = (ls >= 0) ? xz[((size_t)(b * LL + ls)) * (2 * DI) + d] : 0.0f;
        acc = fmaf(cw[d * 4 + k], v, acc);
    }
    xx[t] = acc / (1.0f + expf(-acc));
}

// ---------------- x_dbl = xx @ xproj_w^T  (N=48, K=512) ----------------
__global__ __launch_bounds__(256) void k_xproj(const float* __restrict__ xx,
                                               const float* __restrict__ w,
                                               float* __restrict__ xdbl) {
    int t = blockIdx.x * 256 + threadIdx.x;  // NBL*48 threads
    int e = t % 48;
    int bl = t / 48;
    const float4* xr = (const float4*)(xx + (size_t)bl * DI);
    const float4* wr = (const float4*)(w + (size_t)e * DI);
    float acc = 0.0f;
#pragma unroll 4
    for (int q = 0; q < DI / 4; ++q) {
        float4 xv = xr[q], wv = wr[q];
        acc = fmaf(xv.x, wv.x, acc);
        acc = fmaf(xv.y, wv.y, acc);
        acc = fmaf(xv.z, wv.z, acc);
        acc = fmaf(xv.w, wv.w, acc);
    }
    xdbl[t] = acc;
}

// ---------------- delta = softplus(x_dbl[:, :16] @ dt_w^T + dt_b) ----------------
__global__ __launch_bounds__(256) void k_dtproj(const float* __restrict__ xdbl,
                                                const float* __restrict__ dtw,
                                                const float* __restrict__ dtb,
                                                float* __restrict__ delta) {
    int t = blockIdx.x * 256 + threadIdx.x;  // NBL*DI
    int d = t & (DI - 1);
    int bl = t >> 9;
    const float* xr = xdbl + (size_t)bl * 48;
    const float* wr = dtw + (size_t)d * 16;
    float acc = dtb[d];
#pragma unroll
    for (int r = 0; r < 16; ++r) acc = fmaf(xr[r], wr[r], acc);
    delta[t] = (acc > 20.0f) ? acc : log1pf(expf(acc));
}

// ---------------- selective scan (reference formula incl. 1e-12 floor) + gate ----------------
// 16 lanes per (b,d) sequence; lane = state index n
__global__ __launch_bounds__(256) void k_scan(const float* __restrict__ xx,
                                              const float* __restrict__ delta,
                                              const float* __restrict__ xdbl,
                                              const float* __restrict__ xz,
                                              const float* __restrict__ Alog,
                                              const float* __restrict__ Dp,
                                              float* __restrict__ yg) {
    int tid = threadIdx.x;
    int g = (blockIdx.x * 256 + tid) >> 4;  // sequence id = b*DI + d
    int n = tid & 15;
    int d = g & (DI - 1);
    int b = g >> 9;
    float A = -expf(Alog[d * 16 + n]);
    float Dv = Dp[d];

    // pass 1: total sum of dt over l (lane-parallel then 16-lane reduce)
    float dt_end = 0.0f;
#pragma unroll
    for (int j = 0; j < 16; ++j)
        dt_end += delta[((size_t)(b * LL) + n + j * 16) * DI + d];
#pragma unroll
    for (int m = 8; m >= 1; m >>= 1) dt_end += __shfl_xor(dt_end, m);

    float Dtc = 0.0f, acc = 0.0f;
    for (int l = 0; l < LL; ++l) {
        size_t bld = ((size_t)(b * LL) + l) * DI + d;
        float dtv = delta[bld];
        Dtc += dtv;
        float u = xx[bld];
        const float* xd = xdbl + ((size_t)(b * LL) + l) * 48;
        float Bv = xd[16 + n];
        float Cv = xd[32 + n];
        float s = A * (dt_end - Dtc);  // suffix sum of dA over (l, L-1]
        float dAc = expf(s);
        acc = fmaf(dtv * u * Bv, dAc, acc);
        float xv = acc / (dAc + 1e-12f);
        float part = xv * Cv;
        part += __shfl_xor(part, 1);
        part += __shfl_xor(part, 2);
        part += __shfl_xor(part, 4);
        part += __shfl_xor(part, 8);
        if (n == 0) {
            float yv = fmaf(u, Dv, part);
            float res = xz[((size_t)(b * LL) + l) * (2 * DI) + DI + d];
            yg[bld] = yv * (res / (1.0f + expf(-res)));
        }
    }
}

// ---------------- phase C: x_w[b,w,dm] = mean_h( m[b,h,dm] * x0[b,dm,h,w] ) ----------------
__global__ __launch_bounds__(256) void k_fuse_mean_h(const float* __restrict__ m,
                                                     const float* __restrict__ x0,
                                                     float* __restrict__ xw) {
    int bd = blockIdx.x;  // b*DM + d
    int b = bd >> 8, d = bd & 255;
    int w = threadIdx.x;
    __shared__ float ms[HH];
    ms[w] = m[((size_t)(b * LL) + w) * DM + d];
    __syncthreads();
    const float* xrow = x0 + (size_t)bd * HH * WW;
    float acc = 0.0f;
    for (int h = 0; h < HH; ++h) acc = fmaf(ms[h], xrow[(size_t)h * WW + w], acc);
    xw[((size_t)(b * LL) + w) * DM + d] = acc * (1.0f / HH);
}

// ---------------- transpose model output (b,w,dm) -> (b,dm,w) ----------------
__global__ __launch_bounds__(256) void k_transpose(const float* __restrict__ mw,
                                                   float* __restrict__ mwT) {
    int t = blockIdx.x * 256 + threadIdx.x;  // output index (b,d,w)
    int w = t & 255;
    int d = (t >> 8) & 255;
    int b = t >> 16;
    mwT[t] = mw[((size_t)(b * LL) + w) * DM + d];
}

// ---------------- phase E: out[b,d,h,w] = mwT[b,d,w] * x0[b,d,h,w] ----------------
__global__ __launch_bounds__(256) void k_final(const float* __restrict__ mwT,
                                               const float* __restrict__ x0,
                                               float* __restrict__ out) {
    size_t t = (size_t)blockIdx.x * 256 + threadIdx.x;  // float4 index
    int w4 = (int)(t & 63);
    int bd = (int)(t >> 14);
    float4 xv = ((const float4*)x0)[t];
    float4 mv = ((const float4*)mwT)[(size_t)bd * 64 + w4];
    float4 o;
    o.x = mv.x * xv.x;
    o.y = mv.y * xv.y;
    o.z = mv.z * xv.z;
    o.w = mv.w * xv.w;
    ((float4*)out)[t] = o;
}

extern "C" void kernel_launch(void* const* d_in, const int* in_sizes, int n_in,
                              void* d_out, int out_size, void* d_ws, size_t ws_size,
                              hipStream_t stream) {
    const float* x0     = (const float*)d_in[0];
    const float* in_w   = (const float*)d_in[1];
    const float* conv_w = (const float*)d_in[2];
    const float* conv_b = (const float*)d_in[3];
    const float* xproj_w= (const float*)d_in[4];
    const float* dt_w   = (const float*)d_in[5];
    const float* dt_b   = (const float*)d_in[6];
    const float* A_log  = (const float*)d_in[7];
    const float* Dp     = (const float*)d_in[8];
    const float* out_w  = (const float*)d_in[9];
    float* out = (float*)d_out;

    float* S0   = (float*)d_ws;            // 262144
    float* S1   = S0 + 262144;             // 262144
    float* S2   = S1 + 262144;             // 262144
    float* xz   = S2 + 262144;             // 1048576
    float* xx   = xz + 1048576;            // 524288
    float* xdbl = xx + 524288;             // 49152
    float* delta= xdbl + 49152;            // 524288
    float* yg   = delta + 524288;          // 524288

    auto run_block = [&](const float* in, float* outb, int layer) {
        k_gemm_nt<<<dim3((2 * DI) / 64, NBL / 64), 256, 0, stream>>>(
            in, in_w + (size_t)layer * 2 * DI * DM, xz, NBL, 2 * DI, DM);
        k_conv_silu<<<2048, 256, 0, stream>>>(
            xz, conv_w + (size_t)layer * DI * 4, conv_b + (size_t)layer * DI, xx);
        k_xproj<<<(NBL * 48) / 256, 256, 0, stream>>>(
            xx, xproj_w + (size_t)layer * 48 * DI, xdbl);
        k_dtproj<<<2048, 256, 0, stream>>>(
            xdbl, dt_w + (size_t)layer * DI * 16, dt_b + (size_t)layer * DI, delta);
        k_scan<<<128, 256, 0, stream>>>(
            xx, delta, xdbl, xz, A_log + (size_t)layer * DI * 16, Dp + (size_t)layer * DI, yg);
        k_gemm_nt<<<dim3(DM / 64, NBL / 64), 256, 0, stream>>>(
            yg, out_w + (size_t)layer * DM * DI, outb, NBL, DM, DI);
    };

    // phase A
    k_mean_w<<<65536, 256, 0, stream>>>(x0, S0);
    // model 1 (over H sequences)
    run_block(S0, S1, 0);
    run_block(S1, S2, 1);
    // phase C (fused multiply + mean over H)
    k_fuse_mean_h<<<BSZ * DM, 256, 0, stream>>>(S2, x0, S0);
    // model 2 (over W sequences)
    run_block(S0, S1, 0);
    run_block(S1, S2, 1);
    // phase E
    k_transpose<<<(BSZ * DM * WW) / 256, 256, 0, stream>>>(S2, S1);
    k_final<<<65536, 256, 0, stream>>>(S1, x0, out);
}

// Round 2
// 778.983 us; speedup vs baseline: 1.6904x; 1.6904x over previous
//
#include <hip/hip_runtime.h>
#include <math.h>

#define BSZ 4
#define DM 256
#define HH 256
#define WW 256
#define LL 256
#define DI 512
#define NBL (BSZ * LL)  // 1024

// ---------------- phase A: x_h = mean over W ----------------
__global__ __launch_bounds__(256) void k_mean_w(const float* __restrict__ x0,
                                                float* __restrict__ xseq) {
    int wave = (blockIdx.x * blockDim.x + threadIdx.x) >> 6;
    int lane = threadIdx.x & 63;
    int b = wave >> 16;
    int d = (wave >> 8) & 255;
    int h = wave & 255;
    const float4* row = (const float4*)(x0 + (size_t)wave * WW);
    float4 v = row[lane];
    float s = v.x + v.y + v.z + v.w;
#pragma unroll
    for (int m = 32; m >= 1; m >>= 1) s += __shfl_xor(s, m);
    if (lane == 0) xseq[((size_t)(b * LL) + h) * DM + d] = s * (1.0f / WW);
}

// ---------------- generic fp32 GEMM: C[M,N] = A[M,K] * B[N,K]^T ----------------
__global__ __launch_bounds__(256) void k_gemm_nt(const float* __restrict__ A,
                                                 const float* __restrict__ Bw,
                                                 float* __restrict__ C,
                                                 int M, int N, int K) {
    __shared__ float As[16][64];
    __shared__ float Bs[16][64];
    int tid = threadIdx.x;
    int tx = tid & 15, ty = tid >> 4;
    int n0 = blockIdx.x * 64;
    int m0 = blockIdx.y * 64;
    int lr = tid >> 2;
    int lk = (tid & 3) * 4;

    float acc[4][4];
#pragma unroll
    for (int i = 0; i < 4; ++i)
#pragma unroll
        for (int j = 0; j < 4; ++j) acc[i][j] = 0.0f;

    for (int k0 = 0; k0 < K; k0 += 16) {
        float4 a = *(const float4*)(A + (size_t)(m0 + lr) * K + k0 + lk);
        float4 b = *(const float4*)(Bw + (size_t)(n0 + lr) * K + k0 + lk);
        __syncthreads();
        As[lk + 0][lr] = a.x; As[lk + 1][lr] = a.y; As[lk + 2][lr] = a.z; As[lk + 3][lr] = a.w;
        Bs[lk + 0][lr] = b.x; Bs[lk + 1][lr] = b.y; Bs[lk + 2][lr] = b.z; Bs[lk + 3][lr] = b.w;
        __syncthreads();
#pragma unroll
        for (int kk = 0; kk < 16; ++kk) {
            float4 af = *(const float4*)(&As[kk][ty << 2]);
            float4 bf = *(const float4*)(&Bs[kk][tx << 2]);
            float aa[4] = {af.x, af.y, af.z, af.w};
            float bb[4] = {bf.x, bf.y, bf.z, bf.w};
#pragma unroll
            for (int i = 0; i < 4; ++i)
#pragma unroll
                for (int j = 0; j < 4; ++j) acc[i][j] = fmaf(aa[i], bb[j], acc[i][j]);
        }
    }
#pragma unroll
    for (int i = 0; i < 4; ++i)
#pragma unroll
        for (int j = 0; j < 4; ++j)
            C[(size_t)(m0 + (ty << 2) + i) * N + n0 + (tx << 2) + j] = acc[i][j];
}

// ---------------- causal depthwise conv (D_CONV=4) + silu ----------------
__global__ __launch_bounds__(256) void k_conv_silu(const float* __restrict__ xz,
                                                   const float* __restrict__ cw,
                                                   const float* __restrict__ cb,
                                                   float* __restrict__ xx) {
    int t = blockIdx.x * 256 + threadIdx.x;
    int d = t & (DI - 1);
    int bl = t >> 9;
    int l = bl & (LL - 1);
    int b = bl >> 8;
    float acc = cb[d];
#pragma unroll
    for (int k = 0; k < 4; ++k) {
        int ls = l + k - 3;
        float v = (ls >= 0) ? xz[((size_t)(b * LL + ls)) * (2 * DI) + d] : 0.0f;
        acc = fmaf(cw[d * 4 + k], v, acc);
    }
    xx[t] = acc / (1.0f + expf(-acc));
}

// ---------------- x_dbl = xx @ xproj_w^T  (N=48, K=512) ----------------
__global__ __launch_bounds__(256) void k_xproj(const float* __restrict__ xx,
                                               const float* __restrict__ w,
                                               float* __restrict__ xdbl) {
    int t = blockIdx.x * 256 + threadIdx.x;
    int e = t % 48;
    int bl = t / 48;
    const float4* xr = (const float4*)(xx + (size_t)bl * DI);
    const float4* wr = (const float4*)(w + (size_t)e * DI);
    float acc = 0.0f;
#pragma unroll 4
    for (int q = 0; q < DI / 4; ++q) {
        float4 xv = xr[q], wv = wr[q];
        acc = fmaf(xv.x, wv.x, acc);
        acc = fmaf(xv.y, wv.y, acc);
        acc = fmaf(xv.z, wv.z, acc);
        acc = fmaf(xv.w, wv.w, acc);
    }
    xdbl[t] = acc;
}

// ---------------- delta = softplus(x_dbl[:, :16] @ dt_w^T + dt_b) ----------------
__global__ __launch_bounds__(256) void k_dtproj(const float* __restrict__ xdbl,
                                                const float* __restrict__ dtw,
                                                const float* __restrict__ dtb,
                                                float* __restrict__ delta) {
    int t = blockIdx.x * 256 + threadIdx.x;
    int d = t & (DI - 1);
    int bl = t >> 9;
    const float* xr = xdbl + (size_t)bl * 48;
    const float* wr = dtw + (size_t)d * 16;
    float acc = dtb[d];
#pragma unroll
    for (int r = 0; r < 16; ++r) acc = fmaf(xr[r], wr[r], acc);
    delta[t] = (acc > 20.0f) ? acc : log1pf(expf(acc));
}

// ---------------- parallel selective scan: one block per (b,d) sequence ----------------
// thread l = position l. Prefix sums over l via wave shuffle scan + 4-wave LDS combine.
__device__ __forceinline__ float block_scan_incl(float v, volatile float* ws,
                                                 int lane, int wave, float* total) {
#pragma unroll
    for (int off = 1; off < 64; off <<= 1) {
        float t = __shfl_up(v, off);
        if (lane >= off) v += t;
    }
    __syncthreads();                 // protect ws from previous iteration's readers
    if (lane == 63) ws[wave] = v;
    __syncthreads();
    float base = 0.0f;
#pragma unroll
    for (int wv = 0; wv < 3; ++wv)
        if (wv < wave) base += ws[wv];
    *total = ws[0] + ws[1] + ws[2] + ws[3];
    return v + base;
}

__global__ __launch_bounds__(256) void k_scan(const float* __restrict__ xx,
                                              const float* __restrict__ delta,
                                              const float* __restrict__ xdbl,
                                              const float* __restrict__ xz,
                                              const float* __restrict__ Alog,
                                              const float* __restrict__ Dp,
                                              float* __restrict__ yg) {
    __shared__ float ws[4];
    __shared__ float A_s[16];
    int bd = blockIdx.x;           // b*DI + d
    int d = bd & (DI - 1);
    int b = bd >> 9;
    int l = threadIdx.x;
    int lane = l & 63, wave = l >> 6;

    if (l < 16) A_s[l] = -expf(Alog[d * 16 + l]);

    size_t bld = ((size_t)(b * LL) + l) * DI + d;
    float dtv = delta[bld];
    float u = xx[bld];
    const float* xd = xdbl + ((size_t)(b * LL) + l) * 48;

    float dt_end;
    float Dtc = block_scan_incl(dtv, ws, lane, wave, &dt_end);  // inclusive prefix

    float dtu = dtv * u;
    float y = 0.0f;
#pragma unroll 1
    for (int n = 0; n < 16; ++n) {
        float dAc = expf(A_s[n] * (dt_end - Dtc));
        float term = dtu * xd[16 + n] * dAc;
        float tot;
        float sc = block_scan_incl(term, ws, lane, wave, &tot);
        y = fmaf(sc / (dAc + 1e-12f), xd[32 + n], y);
    }

    float yv = fmaf(u, Dp[d], y);
    float res = xz[((size_t)(b * LL) + l) * (2 * DI) + DI + d];
    yg[bld] = yv * (res / (1.0f + expf(-res)));
}

// ---------------- phase C: x_w[b,w,dm] = mean_h( m[b,h,dm] * x0[b,dm,h,w] ) ----------------
__global__ __launch_bounds__(256) void k_fuse_mean_h(const float* __restrict__ m,
                                                     const float* __restrict__ x0,
                                                     float* __restrict__ xw) {
    int bd = blockIdx.x;
    int b = bd >> 8, d = bd & 255;
    int w = threadIdx.x;
    __shared__ float ms[HH];
    ms[w] = m[((size_t)(b * LL) + w) * DM + d];
    __syncthreads();
    const float* xrow = x0 + (size_t)bd * HH * WW;
    float acc = 0.0f;
    for (int h = 0; h < HH; ++h) acc = fmaf(ms[h], xrow[(size_t)h * WW + w], acc);
    xw[((size_t)(b * LL) + w) * DM + d] = acc * (1.0f / HH);
}

// ---------------- transpose model output (b,w,dm) -> (b,dm,w) ----------------
__global__ __launch_bounds__(256) void k_transpose(const float* __restrict__ mw,
                                                   float* __restrict__ mwT) {
    int t = blockIdx.x * 256 + threadIdx.x;
    int w = t & 255;
    int d = (t >> 8) & 255;
    int b = t >> 16;
    mwT[t] = mw[((size_t)(b * LL) + w) * DM + d];
}

// ---------------- phase E: out[b,d,h,w] = mwT[b,d,w] * x0[b,d,h,w] ----------------
__global__ __launch_bounds__(256) void k_final(const float* __restrict__ mwT,
                                               const float* __restrict__ x0,
                                               float* __restrict__ out) {
    size_t t = (size_t)blockIdx.x * 256 + threadIdx.x;
    int w4 = (int)(t & 63);
    int bd = (int)(t >> 14);
    float4 xv = ((const float4*)x0)[t];
    float4 mv = ((const float4*)mwT)[(size_t)bd * 64 + w4];
    float4 o;
    o.x = mv.x * xv.x;
    o.y = mv.y * xv.y;
    o.z = mv.z * xv.z;
    o.w = mv.w * xv.w;
    ((float4*)out)[t] = o;
}

extern "C" void kernel_launch(void* const* d_in, const int* in_sizes, int n_in,
                              void* d_out, int out_size, void* d_ws, size_t ws_size,
                              hipStream_t stream) {
    const float* x0     = (const float*)d_in[0];
    const float* in_w   = (const float*)d_in[1];
    const float* conv_w = (const float*)d_in[2];
    const float* conv_b = (const float*)d_in[3];
    const float* xproj_w= (const float*)d_in[4];
    const float* dt_w   = (const float*)d_in[5];
    const float* dt_b   = (const float*)d_in[6];
    const float* A_log  = (const float*)d_in[7];
    const float* Dp     = (const float*)d_in[8];
    const float* out_w  = (const float*)d_in[9];
    float* out = (float*)d_out;

    float* S0   = (float*)d_ws;
    float* S1   = S0 + 262144;
    float* S2   = S1 + 262144;
    float* xz   = S2 + 262144;
    float* xx   = xz + 1048576;
    float* xdbl = xx + 524288;
    float* delta= xdbl + 49152;
    float* yg   = delta + 524288;

    auto run_block = [&](const float* in, float* outb, int layer) {
        k_gemm_nt<<<dim3((2 * DI) / 64, NBL / 64), 256, 0, stream>>>(
            in, in_w + (size_t)layer * 2 * DI * DM, xz, NBL, 2 * DI, DM);
        k_conv_silu<<<2048, 256, 0, stream>>>(
            xz, conv_w + (size_t)layer * DI * 4, conv_b + (size_t)layer * DI, xx);
        k_xproj<<<(NBL * 48) / 256, 256, 0, stream>>>(
            xx, xproj_w + (size_t)layer * 48 * DI, xdbl);
        k_dtproj<<<2048, 256, 0, stream>>>(
            xdbl, dt_w + (size_t)layer * DI * 16, dt_b + (size_t)layer * DI, delta);
        k_scan<<<BSZ * DI, 256, 0, stream>>>(
            xx, delta, xdbl, xz, A_log + (size_t)layer * DI * 16, Dp + (size_t)layer * DI, yg);
        k_gemm_nt<<<dim3(DM / 64, NBL / 64), 256, 0, stream>>>(
            yg, out_w + (size_t)layer * DM * DI, outb, NBL, DM, DI);
    };

    k_mean_w<<<65536, 256, 0, stream>>>(x0, S0);
    run_block(S0, S1, 0);
    run_block(S1, S2, 1);
    k_fuse_mean_h<<<BSZ * DM, 256, 0, stream>>>(S2, x0, S0);
    run_block(S0, S1, 0);
    run_block(S1, S2, 1);
    k_transpose<<<(BSZ * DM * WW) / 256, 256, 0, stream>>>(S2, S1);
    k_final<<<65536, 256, 0, stream>>>(S1, x0, out);
}

// Round 3
// 568.272 us; speedup vs baseline: 2.3172x; 1.3708x over previous
//
#include <hip/hip_runtime.h>
#include <math.h>

#define BSZ 4
#define DM 256
#define HH 256
#define WW 256
#define LL 256
#define DI 512
#define NBL (BSZ * LL)  // 1024

// ---------------- phase A: x_h = mean over W ----------------
__global__ __launch_bounds__(256) void k_mean_w(const float* __restrict__ x0,
                                                float* __restrict__ xseq) {
    int wave = (blockIdx.x * blockDim.x + threadIdx.x) >> 6;
    int lane = threadIdx.x & 63;
    int b = wave >> 16;
    int d = (wave >> 8) & 255;
    int h = wave & 255;
    const float4* row = (const float4*)(x0 + (size_t)wave * WW);
    float4 v = row[lane];
    float s = v.x + v.y + v.z + v.w;
#pragma unroll
    for (int m = 32; m >= 1; m >>= 1) s += __shfl_xor(s, m);
    if (lane == 0) xseq[((size_t)(b * LL) + h) * DM + d] = s * (1.0f / WW);
}

// ---------------- fp32 GEMM: C[M,N] = A[M,K] * B[N,K]^T, tile 32x64 ----------------
__global__ __launch_bounds__(256) void k_gemm_nt32(const float* __restrict__ A,
                                                   const float* __restrict__ Bw,
                                                   float* __restrict__ C,
                                                   int M, int N, int K) {
    __shared__ float As[16][32];
    __shared__ float Bs[16][64];
    int tid = threadIdx.x;
    int tx = tid & 15, ty = tid >> 4;   // n-quad, m-pair
    int n0 = blockIdx.x * 64;
    int m0 = blockIdx.y * 32;
    int lr = tid >> 2;
    int lk = (tid & 3) * 4;

    float acc[2][4];
#pragma unroll
    for (int i = 0; i < 2; ++i)
#pragma unroll
        for (int j = 0; j < 4; ++j) acc[i][j] = 0.0f;

    for (int k0 = 0; k0 < K; k0 += 16) {
        float4 bv = *(const float4*)(Bw + (size_t)(n0 + lr) * K + k0 + lk);
        float4 av;
        if (tid < 128) av = *(const float4*)(A + (size_t)(m0 + lr) * K + k0 + lk);
        __syncthreads();
        Bs[lk + 0][lr] = bv.x; Bs[lk + 1][lr] = bv.y; Bs[lk + 2][lr] = bv.z; Bs[lk + 3][lr] = bv.w;
        if (tid < 128) {
            As[lk + 0][lr] = av.x; As[lk + 1][lr] = av.y; As[lk + 2][lr] = av.z; As[lk + 3][lr] = av.w;
        }
        __syncthreads();
#pragma unroll
        for (int kk = 0; kk < 16; ++kk) {
            float a0 = As[kk][ty * 2 + 0];
            float a1 = As[kk][ty * 2 + 1];
            float4 bf = *(const float4*)(&Bs[kk][tx << 2]);
            float bb[4] = {bf.x, bf.y, bf.z, bf.w};
#pragma unroll
            for (int j = 0; j < 4; ++j) {
                acc[0][j] = fmaf(a0, bb[j], acc[0][j]);
                acc[1][j] = fmaf(a1, bb[j], acc[1][j]);
            }
        }
    }
#pragma unroll
    for (int i = 0; i < 2; ++i)
#pragma unroll
        for (int j = 0; j < 4; ++j)
            C[(size_t)(m0 + ty * 2 + i) * N + n0 + (tx << 2) + j] = acc[i][j];
}

// ---------------- fused conv+silu+xproj: one block per (b,l) ----------------
__global__ __launch_bounds__(256) void k_mid(const float* __restrict__ xz,
                                             const float* __restrict__ cw,
                                             const float* __restrict__ cb,
                                             const float* __restrict__ xpw,
                                             float* __restrict__ xx,
                                             float* __restrict__ xdbl) {
    __shared__ float xs[DI];
    __shared__ float pr[256];
    int bl = blockIdx.x;
    int b = bl >> 8, l = bl & 255;
    int tid = threadIdx.x;

    // depthwise causal conv (D_CONV=4) + silu; 2 channels per thread
#pragma unroll
    for (int c = 0; c < 2; ++c) {
        int d = tid + 256 * c;
        float4 w4 = *(const float4*)(cw + d * 4);
        float wk[4] = {w4.x, w4.y, w4.z, w4.w};
        float acc = cb[d];
#pragma unroll
        for (int k = 0; k < 4; ++k) {
            int ls = l + k - 3;
            float v = (ls >= 0) ? xz[((size_t)(b * LL + ls)) * (2 * DI) + d] : 0.0f;
            acc = fmaf(wk[k], v, acc);
        }
        float v = acc / (1.0f + expf(-acc));
        xs[d] = v;
        xx[(size_t)bl * DI + d] = v;
    }
    __syncthreads();

    // xdbl[e] = dot(xs, xpw[e]) for e in [0,48); 4 partial chunks per dot
    int e = tid >> 2, c = tid & 3;
    float a = 0.0f;
    if (e < 48) {
        const float4* xv = (const float4*)(xs + c * 128);
        const float4* wv = (const float4*)(xpw + (size_t)e * DI + c * 128);
#pragma unroll 8
        for (int q = 0; q < 32; ++q) {
            float4 x4 = xv[q], p4 = wv[q];
            a = fmaf(x4.x, p4.x, a);
            a = fmaf(x4.y, p4.y, a);
            a = fmaf(x4.z, p4.z, a);
            a = fmaf(x4.w, p4.w, a);
        }
    }
    pr[tid] = a;
    __syncthreads();
    if (tid < 48)
        xdbl[(size_t)bl * 48 + tid] = pr[4 * tid] + pr[4 * tid + 1] + pr[4 * tid + 2] + pr[4 * tid + 3];
}

// ---------------- selective scan: one block per (b,d); 4 waves x 4 states ----------------
// lane k of each wave holds positions l = 4k..4k+3 (blocked). dtproj fused in.
__global__ __launch_bounds__(256) void k_scan(const float* __restrict__ xx,
                                              const float* __restrict__ xdbl,
                                              const float* __restrict__ xz,
                                              const float* __restrict__ Alog,
                                              const float* __restrict__ Dp,
                                              const float* __restrict__ dtw,
                                              const float* __restrict__ dtb,
                                              float* __restrict__ yg) {
    __shared__ float yred[4][LL];
    __shared__ float us[LL];
    int tid = threadIdx.x;
    int lane = tid & 63, w = tid >> 6;
    int seq = blockIdx.x;              // b*DI + d
    int d = seq & (DI - 1), b = seq >> 9;
    int l0 = lane * 4;

    const float* xd0 = xdbl + ((size_t)(b * LL) + l0) * 48;

    // dt_w row (uniform per block)
    const float* wr = dtw + d * 16;
    float4 w0 = *(const float4*)(wr + 0);
    float4 w1 = *(const float4*)(wr + 4);
    float4 w2 = *(const float4*)(wr + 8);
    float4 w3 = *(const float4*)(wr + 12);
    float bias = dtb[d];

    float dt[4], u[4], dtu[4], P[4];
#pragma unroll
    for (int i = 0; i < 4; ++i) {
        const float* xr = xd0 + i * 48;
        float4 a0 = *(const float4*)(xr + 0);
        float4 a1 = *(const float4*)(xr + 4);
        float4 a2 = *(const float4*)(xr + 8);
        float4 a3 = *(const float4*)(xr + 12);
        float acc = bias;
        acc = fmaf(a0.x, w0.x, acc); acc = fmaf(a0.y, w0.y, acc);
        acc = fmaf(a0.z, w0.z, acc); acc = fmaf(a0.w, w0.w, acc);
        acc = fmaf(a1.x, w1.x, acc); acc = fmaf(a1.y, w1.y, acc);
        acc = fmaf(a1.z, w1.z, acc); acc = fmaf(a1.w, w1.w, acc);
        acc = fmaf(a2.x, w2.x, acc); acc = fmaf(a2.y, w2.y, acc);
        acc = fmaf(a2.z, w2.z, acc); acc = fmaf(a2.w, w2.w, acc);
        acc = fmaf(a3.x, w3.x, acc); acc = fmaf(a3.y, w3.y, acc);
        acc = fmaf(a3.z, w3.z, acc); acc = fmaf(a3.w, w3.w, acc);
        dt[i] = (acc > 20.0f) ? acc : log1pf(expf(acc));
        u[i] = xx[((size_t)(b * LL) + l0 + i) * DI + d];
        dtu[i] = dt[i] * u[i];
    }

    // inclusive prefix of dt over the whole sequence (blocked layout)
    P[0] = dt[0]; P[1] = P[0] + dt[1]; P[2] = P[1] + dt[2]; P[3] = P[2] + dt[3];
    float s = P[3];
#pragma unroll
    for (int off = 1; off < 64; off <<= 1) {
        float t = __shfl_up(s, off);
        if (lane >= off) s += t;
    }
    float base = s - P[3];
    float dt_end = __shfl(s, 63);
    float Dtc[4];
#pragma unroll
    for (int i = 0; i < 4; ++i) Dtc[i] = P[i] + base;

    if (w == 0) {
#pragma unroll
        for (int i = 0; i < 4; ++i) us[l0 + i] = u[i];
    }

    // this wave handles states n = 4w .. 4w+3
    float4 Al = *(const float4*)(Alog + d * 16 + 4 * w);
    float A[4] = {-expf(Al.x), -expf(Al.y), -expf(Al.z), -expf(Al.w)};
    float Bv[4][4], Cv[4][4];
#pragma unroll
    for (int i = 0; i < 4; ++i) {
        float4 bq = *(const float4*)(xd0 + i * 48 + 16 + 4 * w);
        float4 cq = *(const float4*)(xd0 + i * 48 + 32 + 4 * w);
        Bv[i][0] = bq.x; Bv[i][1] = bq.y; Bv[i][2] = bq.z; Bv[i][3] = bq.w;
        Cv[i][0] = cq.x; Cv[i][1] = cq.y; Cv[i][2] = cq.z; Cv[i][3] = cq.w;
    }

    float y[4] = {0.0f, 0.0f, 0.0f, 0.0f};
#pragma unroll
    for (int c = 0; c < 4; ++c) {
        float Ac = A[c];
        float dAc[4], t[4];
#pragma unroll
        for (int i = 0; i < 4; ++i) {
            dAc[i] = expf(Ac * (dt_end - Dtc[i]));
            t[i] = dtu[i] * Bv[i][c] * dAc[i];
        }
        float p0 = t[0], p1 = p0 + t[1], p2 = p1 + t[2], p3 = p2 + t[3];
        float ss = p3;
#pragma unroll
        for (int off = 1; off < 64; off <<= 1) {
            float tt = __shfl_up(ss, off);
            if (lane >= off) ss += tt;
        }
        float baseT = ss - p3;
        y[0] += (p0 + baseT) / (dAc[0] + 1e-12f) * Cv[0][c];
        y[1] += (p1 + baseT) / (dAc[1] + 1e-12f) * Cv[1][c];
        y[2] += (p2 + baseT) / (dAc[2] + 1e-12f) * Cv[2][c];
        y[3] += (p3 + baseT) / (dAc[3] + 1e-12f) * Cv[3][c];
    }
#pragma unroll
    for (int i = 0; i < 4; ++i) yred[w][l0 + i] = y[i];
    __syncthreads();

    // finish: thread = position l
    int l = tid;
    float ysum = yred[0][l] + yred[1][l] + yred[2][l] + yred[3][l];
    float yv = fmaf(us[l], Dp[d], ysum);
    float res = xz[((size_t)(b * LL) + l) * (2 * DI) + DI + d];
    yg[((size_t)(b * LL) + l) * DI + d] = yv * (res / (1.0f + expf(-res)));
}

// ---------------- phase C: x_w[b,w,dm] = mean_h( m[b,h,dm] * x0[b,dm,h,w] ) ----------------
__global__ __launch_bounds__(256) void k_fuse_mean_h(const float* __restrict__ m,
                                                     const float* __restrict__ x0,
                                                     float* __restrict__ xw) {
    int bd = blockIdx.x;
    int b = bd >> 8, d = bd & 255;
    int w = threadIdx.x;
    __shared__ float ms[HH];
    ms[w] = m[((size_t)(b * LL) + w) * DM + d];
    __syncthreads();
    const float* xrow = x0 + (size_t)bd * HH * WW;
    float acc = 0.0f;
    for (int h = 0; h < HH; ++h) acc = fmaf(ms[h], xrow[(size_t)h * WW + w], acc);
    xw[((size_t)(b * LL) + w) * DM + d] = acc * (1.0f / HH);
}

// ---------------- transpose model output (b,w,dm) -> (b,dm,w) ----------------
__global__ __launch_bounds__(256) void k_transpose(const float* __restrict__ mw,
                                                   float* __restrict__ mwT) {
    int t = blockIdx.x * 256 + threadIdx.x;
    int w = t & 255;
    int d = (t >> 8) & 255;
    int b = t >> 16;
    mwT[t] = mw[((size_t)(b * LL) + w) * DM + d];
}

// ---------------- phase E: out[b,d,h,w] = mwT[b,d,w] * x0[b,d,h,w] ----------------
__global__ __launch_bounds__(256) void k_final(const float* __restrict__ mwT,
                                               const float* __restrict__ x0,
                                               float* __restrict__ out) {
    size_t t = (size_t)blockIdx.x * 256 + threadIdx.x;
    int w4 = (int)(t & 63);
    int bd = (int)(t >> 14);
    float4 xv = ((const float4*)x0)[t];
    float4 mv = ((const float4*)mwT)[(size_t)bd * 64 + w4];
    float4 o;
    o.x = mv.x * xv.x;
    o.y = mv.y * xv.y;
    o.z = mv.z * xv.z;
    o.w = mv.w * xv.w;
    ((float4*)out)[t] = o;
}

extern "C" void kernel_launch(void* const* d_in, const int* in_sizes, int n_in,
                              void* d_out, int out_size, void* d_ws, size_t ws_size,
                              hipStream_t stream) {
    const float* x0     = (const float*)d_in[0];
    const float* in_w   = (const float*)d_in[1];
    const float* conv_w = (const float*)d_in[2];
    const float* conv_b = (const float*)d_in[3];
    const float* xproj_w= (const float*)d_in[4];
    const float* dt_w   = (const float*)d_in[5];
    const float* dt_b   = (const float*)d_in[6];
    const float* A_log  = (const float*)d_in[7];
    const float* Dp     = (const float*)d_in[8];
    const float* out_w  = (const float*)d_in[9];
    float* out = (float*)d_out;

    float* S0   = (float*)d_ws;            // NBL*DM
    float* S1   = S0 + 262144;
    float* S2   = S1 + 262144;
    float* xz   = S2 + 262144;             // NBL*2DI
    float* xx   = xz + 1048576;            // NBL*DI
    float* xdbl = xx + 524288;             // NBL*48
    float* yg   = xdbl + 49152;            // NBL*DI

    auto run_block = [&](const float* in, float* outb, int layer) {
        k_gemm_nt32<<<dim3((2 * DI) / 64, NBL / 32), 256, 0, stream>>>(
            in, in_w + (size_t)layer * 2 * DI * DM, xz, NBL, 2 * DI, DM);
        k_mid<<<NBL, 256, 0, stream>>>(
            xz, conv_w + (size_t)layer * DI * 4, conv_b + (size_t)layer * DI,
            xproj_w + (size_t)layer * 48 * DI, xx, xdbl);
        k_scan<<<BSZ * DI, 256, 0, stream>>>(
            xx, xdbl, xz, A_log + (size_t)layer * DI * 16, Dp + (size_t)layer * DI,
            dt_w + (size_t)layer * DI * 16, dt_b + (size_t)layer * DI, yg);
        k_gemm_nt32<<<dim3(DM / 64, NBL / 32), 256, 0, stream>>>(
            yg, out_w + (size_t)layer * DM * DI, outb, NBL, DM, DI);
    };

    k_mean_w<<<65536, 256, 0, stream>>>(x0, S0);
    run_block(S0, S1, 0);
    run_block(S1, S2, 1);
    k_fuse_mean_h<<<BSZ * DM, 256, 0, stream>>>(S2, x0, S0);
    run_block(S0, S1, 0);
    run_block(S1, S2, 1);
    k_transpose<<<(BSZ * DM * WW) / 256, 256, 0, stream>>>(S2, S1);
    k_final<<<65536, 256, 0, stream>>>(S1, x0, out);
}